// Round 4
// baseline (2257.823 us; speedup 1.0000x reference)
//
#include <hip/hip_runtime.h>
#include <stdint.h>

#define HIDDEN 2048
#define INTER 8192
#define RANK 16
#define BATCH 4
#define SEQ 2048
#define MROWS (BATCH * SEQ)   // 8192
#define KSAVE 10
#define FIXCAP (1u << 18)
#define FIX_TAU 1.2e-4f
#define NHALF 4096

typedef unsigned short u16;
typedef __attribute__((ext_vector_type(8))) __bf16 bf16x8;
typedef __attribute__((ext_vector_type(4))) float f32x4;

__device__ __forceinline__ float bf16_to_f32(u16 h) {
    return __uint_as_float(((unsigned int)h) << 16);
}
__device__ __forceinline__ u16 f32_to_bf16(float f) {
    unsigned int u = __float_as_uint(f);
    u += 0x7fffu + ((u >> 16) & 1u);   // RNE; finite inputs
    return (u16)(u >> 16);
}
__device__ __forceinline__ void split_bf16(float v, u16& h, u16& l) {
    h = f32_to_bf16(v);
    l = f32_to_bf16(v - bf16_to_f32(h));
}

// ============================================================================
// MFMA machinery (16x16x32 bf16). LDS tiles: rows of 32 k as 4 chunks of 16B,
// chunk index = r*4 + (c ^ ((r>>1)&3))  (verified conflict-free in r3).
// ============================================================================
#define TILE_SH (128 * 32)   // u16 elements per 128-row tile (8 KB)

__device__ __forceinline__ int swz_chunk(int r, int c) {
    return r * 4 + (c ^ ((r >> 1) & 3));
}

// stage NCH 16B-chunks (NCH/4 rows) from row-major global via global_load_lds.
// 512-thread block: each wave fills 64 consecutive chunks per pass.
template <int NCH>
__device__ __forceinline__ void stage_tileN(const u16* g, int ldk, u16* lds, int tid) {
    int wid = tid >> 6, lane = tid & 63;
#pragma unroll
    for (int c0 = 0; c0 < NCH; c0 += 512) {
        int ch = c0 + wid * 64 + lane;
        int r = ch >> 2;
        int c = (ch & 3) ^ ((r >> 1) & 3);
        const u16* src = g + (size_t)r * ldk + c * 8;
        u16* dst = lds + (size_t)(c0 + wid * 64) * 8;   // wave-uniform base
        __builtin_amdgcn_global_load_lds(
            (const __attribute__((address_space(1))) void*)src,
            (__attribute__((address_space(3))) void*)dst, 16, 0, 0);
    }
}

__device__ __forceinline__ bf16x8 read_frag(const u16* lds, int r, int q) {
    return *(const bf16x8*)(lds + swz_chunk(r, q) * 8);
}

// ---------- up GEMM v3: 128x256 tile, 512 thr, in-kernel trunc-split A,
// 3-term split MFMA, relu+bf16 out, fused zero-count, borderline fix list ----
__global__ __launch_bounds__(512) void gemm_up_mfma3(
    const float* __restrict__ x1,
    const u16* __restrict__ wth, const u16* __restrict__ wtl,
    const float* __restrict__ t1, const float* __restrict__ upB,
    u16* __restrict__ x2, int* __restrict__ counts,
    unsigned* __restrict__ fixctr, unsigned* __restrict__ fixlist,
    int noff)
{
    __shared__ u16 Ah[TILE_SH], Al[TILE_SH];
    __shared__ u16 Bh[2 * TILE_SH], Bl[2 * TILE_SH];
    int tid = threadIdx.x, lane = tid & 63, wid = tid >> 6;
    int wr = wid >> 2, wc = wid & 3;          // 2 x 4 wave grid
    int col = lane & 15, q = lane >> 4;

    // swizzle: groups of 4 n-supers x 64 m-blocks
    int bid = blockIdx.y * gridDim.x + blockIdx.x;   // grid (16, 64) -> 1024
    int g = bid >> 8, within = bid & 255;
    int nb = g * 4 + (within & 3);
    int mb = within >> 2;
    int m0 = mb * 128, n0l = nb * 256, n0g = noff + n0l;

    f32x4 acc[4][4];
#pragma unroll
    for (int i = 0; i < 4; ++i)
#pragma unroll
        for (int j = 0; j < 4; ++j) acc[i][j] = (f32x4){0.f, 0.f, 0.f, 0.f};

    const float* ga = x1 + (size_t)m0 * HIDDEN;
    const u16* gb_h = wth + (size_t)n0l * HIDDEN;
    const u16* gb_l = wtl + (size_t)n0l * HIDDEN;
    int f4 = tid & 7;        // float4 col within 32-k tile
    int rA = tid >> 3;       // base row 0..63

    for (int k0 = 0; k0 < HIDDEN; k0 += 32) {
        stage_tileN<1024>(gb_h + k0, HIDDEN, Bh, tid);
        stage_tileN<1024>(gb_l + k0, HIDDEN, Bl, tid);
        // A: load fp32, truncation-split hi/lo bf16, store LDS
#pragma unroll
        for (int h = 0; h < 2; ++h) {
            int row = rA + h * 64;
            float4 v = *(const float4*)(ga + (size_t)row * HIDDEN + k0 + f4 * 4);
            unsigned hx0 = __float_as_uint(v.x) & 0xffff0000u;
            unsigned hx1 = __float_as_uint(v.y) & 0xffff0000u;
            unsigned hx2 = __float_as_uint(v.z) & 0xffff0000u;
            unsigned hx3 = __float_as_uint(v.w) & 0xffff0000u;
            float l0 = v.x - __uint_as_float(hx0);
            float l1 = v.y - __uint_as_float(hx1);
            float l2 = v.z - __uint_as_float(hx2);
            float l3 = v.w - __uint_as_float(hx3);
            unsigned lo0 = __float_as_uint(l0) & 0xffff0000u;
            unsigned lo1 = __float_as_uint(l1) & 0xffff0000u;
            unsigned lo2 = __float_as_uint(l2) & 0xffff0000u;
            unsigned lo3 = __float_as_uint(l3) & 0xffff0000u;
            uint2 hp = {(hx0 >> 16) | hx1, (hx2 >> 16) | hx3};
            uint2 lp = {(lo0 >> 16) | lo1, (lo2 >> 16) | lo3};
            int pos = swz_chunk(row, f4 >> 1) * 8 + (f4 & 1) * 4;
            *(uint2*)(Ah + pos) = hp;
            *(uint2*)(Al + pos) = lp;
        }
        __syncthreads();
        bf16x8 ah[4], al[4];
#pragma unroll
        for (int i = 0; i < 4; ++i) {
            int r = wr * 64 + i * 16 + col;
            ah[i] = read_frag(Ah, r, q);
            al[i] = read_frag(Al, r, q);
        }
#pragma unroll
        for (int j = 0; j < 4; ++j) {
            int rr = wc * 64 + j * 16 + col;          // 0..255
            bf16x8 bh = read_frag(Bh, rr, q);
            bf16x8 bl = read_frag(Bl, rr, q);
#pragma unroll
            for (int i = 0; i < 4; ++i) {
                acc[i][j] = __builtin_amdgcn_mfma_f32_16x16x32_bf16(ah[i], bh, acc[i][j], 0, 0, 0);
                acc[i][j] = __builtin_amdgcn_mfma_f32_16x16x32_bf16(al[i], bh, acc[i][j], 0, 0, 0);
                acc[i][j] = __builtin_amdgcn_mfma_f32_16x16x32_bf16(ah[i], bl, acc[i][j], 0, 0, 0);
            }
        }
        __syncthreads();
    }

    // LoRA as one extra split-MFMA K-step (K=16 real + 16 zero pad)
    for (int idx = tid; idx < 4096; idx += 512) {
        int r = idx >> 5, c16 = idx & 31;
        float tv = (c16 < RANK) ? t1[(size_t)(m0 + r) * RANK + c16] : 0.f;
        u16 th, tl2;
        split_bf16(tv, th, tl2);
        int pos = swz_chunk(r, c16 >> 3) * 8 + (c16 & 7);
        Ah[pos] = th; Al[pos] = tl2;
    }
    for (int idx = tid; idx < 8192; idx += 512) {
        int r = idx >> 5, c16 = idx & 31;             // r 0..255
        float uv = (c16 < RANK) ? upB[(size_t)c16 * INTER + n0g + r] : 0.f;
        u16 uh, ul;
        split_bf16(uv, uh, ul);
        int pos = swz_chunk(r, c16 >> 3) * 8 + (c16 & 7);
        Bh[pos] = uh; Bl[pos] = ul;
    }
    __syncthreads();
    {
        bf16x8 ah[4], al[4];
#pragma unroll
        for (int i = 0; i < 4; ++i) {
            int r = wr * 64 + i * 16 + col;
            ah[i] = read_frag(Ah, r, q);
            al[i] = read_frag(Al, r, q);
        }
#pragma unroll
        for (int j = 0; j < 4; ++j) {
            int rr = wc * 64 + j * 16 + col;
            bf16x8 bh = read_frag(Bh, rr, q);
            bf16x8 bl = read_frag(Bl, rr, q);
#pragma unroll
            for (int i = 0; i < 4; ++i) {
                acc[i][j] = __builtin_amdgcn_mfma_f32_16x16x32_bf16(ah[i], bh, acc[i][j], 0, 0, 0);
                acc[i][j] = __builtin_amdgcn_mfma_f32_16x16x32_bf16(al[i], bh, acc[i][j], 0, 0, 0);
                acc[i][j] = __builtin_amdgcn_mfma_f32_16x16x32_bf16(ah[i], bl, acc[i][j], 0, 0, 0);
            }
        }
    }

    // epilogue: relu + bf16 store + fix list + fused zero-count
    int b = m0 >> 11;   // batch (SEQ=2048, 128-row blocks aligned)
#pragma unroll
    for (int j = 0; j < 4; ++j) {
        int n = n0g + wc * 64 + j * 16 + col;
        int zc = 0;
#pragma unroll
        for (int i = 0; i < 4; ++i) {
#pragma unroll
            for (int reg = 0; reg < 4; ++reg) {
                int m = m0 + wr * 64 + i * 16 + q * 4 + reg;
                float v = acc[i][j][reg];
                if (fabsf(v) < FIX_TAU) {
                    unsigned slot = atomicAdd(fixctr, 1u);
                    if (slot < FIXCAP) fixlist[slot] = ((unsigned)m << 13) | (unsigned)n;
                }
                zc += (v <= 0.f) ? 1 : 0;
                float rv = v > 0.f ? v : 0.f;
                x2[(size_t)m * INTER + n] = f32_to_bf16(rv);
            }
        }
        zc += __shfl_down(zc, 32);
        zc += __shfl_down(zc, 16);
        if (lane < 16) atomicAdd(&counts[b * INTER + n], zc);
    }
}

// ---------- down GEMM v2: 128x256 tile, 512 thr, bf16 MFMA, fp32 out ----------
__global__ __launch_bounds__(512) void gemm_down_mfma2(
    const u16* __restrict__ x2, const u16* __restrict__ wdt,
    const float* __restrict__ t2, const float* __restrict__ dnB,
    float* __restrict__ out)
{
    __shared__ u16 As[TILE_SH];
    __shared__ u16 Bs[2 * TILE_SH];
    int tid = threadIdx.x, lane = tid & 63, wid = tid >> 6;
    int wr = wid >> 2, wc = wid & 3;
    int col = lane & 15, q = lane >> 4;
    int m0 = blockIdx.y * 128, n0 = blockIdx.x * 256;

    f32x4 acc[4][4];
#pragma unroll
    for (int i = 0; i < 4; ++i)
#pragma unroll
        for (int j = 0; j < 4; ++j) acc[i][j] = (f32x4){0.f, 0.f, 0.f, 0.f};

    const u16* ga = x2 + (size_t)m0 * INTER;
    const u16* gb = wdt + (size_t)n0 * INTER;

    for (int k0 = 0; k0 < INTER; k0 += 32) {
        stage_tileN<512>(ga + k0, INTER, As, tid);
        stage_tileN<1024>(gb + k0, INTER, Bs, tid);
        __syncthreads();
        bf16x8 af[4];
#pragma unroll
        for (int i = 0; i < 4; ++i) af[i] = read_frag(As, wr * 64 + i * 16 + col, q);
#pragma unroll
        for (int j = 0; j < 4; ++j) {
            bf16x8 bf = read_frag(Bs, wc * 64 + j * 16 + col, q);
#pragma unroll
            for (int i = 0; i < 4; ++i)
                acc[i][j] = __builtin_amdgcn_mfma_f32_16x16x32_bf16(af[i], bf, acc[i][j], 0, 0, 0);
        }
        __syncthreads();
    }

    // LoRA extra K-step
    for (int idx = tid; idx < 4096; idx += 512) {
        int r = idx >> 5, c16 = idx & 31;
        float tv = (c16 < RANK) ? t2[(size_t)(m0 + r) * RANK + c16] : 0.f;
        int pos = swz_chunk(r, c16 >> 3) * 8 + (c16 & 7);
        As[pos] = f32_to_bf16(tv);
    }
    for (int idx = tid; idx < 8192; idx += 512) {
        int r = idx >> 5, c16 = idx & 31;
        float uv = (c16 < RANK) ? dnB[(size_t)c16 * HIDDEN + n0 + r] : 0.f;
        int pos = swz_chunk(r, c16 >> 3) * 8 + (c16 & 7);
        Bs[pos] = f32_to_bf16(uv);
    }
    __syncthreads();
    {
        bf16x8 af[4];
#pragma unroll
        for (int i = 0; i < 4; ++i) af[i] = read_frag(As, wr * 64 + i * 16 + col, q);
#pragma unroll
        for (int j = 0; j < 4; ++j) {
            bf16x8 bf = read_frag(Bs, wc * 64 + j * 16 + col, q);
#pragma unroll
            for (int i = 0; i < 4; ++i)
                acc[i][j] = __builtin_amdgcn_mfma_f32_16x16x32_bf16(af[i], bf, acc[i][j], 0, 0, 0);
        }
    }
#pragma unroll
    for (int i = 0; i < 4; ++i)
#pragma unroll
        for (int j = 0; j < 4; ++j) {
            int n = n0 + wc * 64 + j * 16 + col;
#pragma unroll
            for (int reg = 0; reg < 4; ++reg) {
                int m = m0 + wr * 64 + i * 16 + q * 4 + reg;
                out[(size_t)m * HIDDEN + n] = acc[i][j][reg];
            }
        }
}

// ---------- exact fp32 recompute of borderline y1 elements (+count adjust) ----
__global__ __launch_bounds__(256) void fixup_kernel(
    const float* __restrict__ x1, const float* __restrict__ w_up,
    const float* __restrict__ t1, const float* __restrict__ upB,
    const unsigned* __restrict__ fixctr, const unsigned* __restrict__ fixlist,
    u16* __restrict__ x2, int* __restrict__ counts)
{
    unsigned n_items = *fixctr;
    if (n_items > FIXCAP) n_items = FIXCAP;
    int lane = threadIdx.x & 63;
    int gwave = blockIdx.x * 4 + (threadIdx.x >> 6);
    int nwaves = gridDim.x * 4;
    for (unsigned it = gwave; it < n_items; it += nwaves) {
        unsigned code = fixlist[it];
        int m = code >> 13, n = code & 8191;
        float s = 0.f;
        const float* xr = x1 + (size_t)m * HIDDEN;
        for (int k = lane; k < HIDDEN; k += 64)
            s = fmaf(xr[k], w_up[(size_t)k * INTER + n], s);
#pragma unroll
        for (int off = 32; off > 0; off >>= 1) s += __shfl_down(s, off);
        if (lane == 0) {
            float lo = 0.f;
#pragma unroll
            for (int r = 0; r < RANK; ++r)
                lo = fmaf(t1[(size_t)m * RANK + r], upB[(size_t)r * INTER + n], lo);
            float y = s + lo;
            int oldz = (x2[(size_t)m * INTER + n] == 0) ? 1 : 0;
            int newz = (y <= 0.f) ? 1 : 0;
            if (newz != oldz) atomicAdd(&counts[(m >> 11) * INTER + n], newz - oldz);
            x2[(size_t)m * INTER + n] = f32_to_bf16(y > 0.f ? y : 0.f);
        }
    }
}

// ============================================================================
// transpose+convert: in [R][C-range] f32 -> out [Crange][R] bf16 (hi / hi+lo)
// ============================================================================
template <bool SPLIT>
__global__ __launch_bounds__(256) void transpose_cvt(
    const float* __restrict__ in, u16* __restrict__ outh, u16* __restrict__ outl,
    int R, int C)
{
    __shared__ float t[32][33];
    int x = threadIdx.x & 31, y = threadIdx.x >> 5;
    int r0 = blockIdx.y * 32, c0 = blockIdx.x * 32;
#pragma unroll
    for (int p = 0; p < 4; ++p)
        t[y + p * 8][x] = in[(size_t)(r0 + y + p * 8) * C + c0 + x];
    __syncthreads();
#pragma unroll
    for (int p = 0; p < 4; ++p) {
        float v = t[x][y + p * 8];
        u16 h = f32_to_bf16(v);
        outh[(size_t)(c0 + y + p * 8) * R + r0 + x] = h;
        if (SPLIT)
            outl[(size_t)(c0 + y + p * 8) * R + r0 + x] = f32_to_bf16(v - bf16_to_f32(h));
    }
}

// ============================================================================
// LoRA row-dots (t = X @ A, rank 16)
// ============================================================================
__global__ __launch_bounds__(256) void rowdot16_f32(
    const float* __restrict__ X, const float* __restrict__ A,
    float* __restrict__ T, int K)
{
    __shared__ float red[256][RANK + 1];
    int m = blockIdx.x;
    const float* xr = X + (size_t)m * K;
    float acc[RANK];
#pragma unroll
    for (int r = 0; r < RANK; ++r) acc[r] = 0.f;
    for (int k = threadIdx.x; k < K; k += 256) {
        float xv = xr[k];
        const float* ar = A + (size_t)k * RANK;
#pragma unroll
        for (int r = 0; r < RANK; ++r) acc[r] = fmaf(xv, ar[r], acc[r]);
    }
#pragma unroll
    for (int r = 0; r < RANK; ++r) red[threadIdx.x][r] = acc[r];
    __syncthreads();
    for (int off = 128; off > 0; off >>= 1) {
        if (threadIdx.x < off) {
#pragma unroll
            for (int r = 0; r < RANK; ++r)
                red[threadIdx.x][r] += red[threadIdx.x + off][r];
        }
        __syncthreads();
    }
    if (threadIdx.x < RANK) T[(size_t)m * RANK + threadIdx.x] = red[0][threadIdx.x];
}

__global__ __launch_bounds__(256) void rowdot16_bf16(
    const u16* __restrict__ X, const float* __restrict__ A,
    float* __restrict__ T, int K)
{
    __shared__ float red[256][RANK + 1];
    int m = blockIdx.x;
    const u16* xr = X + (size_t)m * K;
    float acc[RANK];
#pragma unroll
    for (int r = 0; r < RANK; ++r) acc[r] = 0.f;
    for (int k = threadIdx.x * 8; k < K; k += 256 * 8) {
        uint4 p = *(const uint4*)(xr + k);
        unsigned w_[4] = {p.x, p.y, p.z, p.w};
#pragma unroll
        for (int e = 0; e < 4; ++e) {
            float v0 = bf16_to_f32((u16)(w_[e] & 0xffffu));
            float v1 = bf16_to_f32((u16)(w_[e] >> 16));
            const float* ar0 = A + (size_t)(k + 2 * e) * RANK;
            const float* ar1 = A + (size_t)(k + 2 * e + 1) * RANK;
#pragma unroll
            for (int r = 0; r < RANK; ++r)
                acc[r] = fmaf(v0, ar0[r], fmaf(v1, ar1[r], acc[r]));
        }
    }
#pragma unroll
    for (int r = 0; r < RANK; ++r) red[threadIdx.x][r] = acc[r];
    __syncthreads();
    for (int off = 128; off > 0; off >>= 1) {
        if (threadIdx.x < off) {
#pragma unroll
            for (int r = 0; r < RANK; ++r)
                red[threadIdx.x][r] += red[threadIdx.x + off][r];
        }
        __syncthreads();
    }
    if (threadIdx.x < RANK) T[(size_t)m * RANK + threadIdx.x] = red[0][threadIdx.x];
}

// ============================================================================
// fp32 VALU GEMM fallbacks + old 256-thr down MFMA (mid tier) — unchanged
// ============================================================================
#define BM 128
#define BN 128
#define BK 16
#define TM 8

__global__ __launch_bounds__(256) void gemm_up_f32(
    const float* __restrict__ A, const float* __restrict__ B,
    const float* __restrict__ Tl, const float* __restrict__ Bl,
    u16* __restrict__ C, int M, int N, int K)
{
    __shared__ float As[BK][BM + 4];
    __shared__ float Bs[BK][BN];
    int tid = threadIdx.x;
    int tx = tid % 16, ty = tid / 16;
    int m0 = blockIdx.y * BM, n0 = blockIdx.x * BN;
    const float* Ab = A + (size_t)m0 * K;
    const float* Bb = B + n0;
    float acc[TM][8];
#pragma unroll
    for (int i = 0; i < TM; ++i)
#pragma unroll
        for (int j = 0; j < 8; ++j) acc[i][j] = 0.f;

    int arow = tid >> 2, acol = (tid & 3) * 4;
    int brow = tid >> 5, bcol = (tid & 31) * 4;

    for (int k0 = 0; k0 < K; k0 += BK) {
#pragma unroll
        for (int h = 0; h < 2; ++h) {
            int r = arow + h * 64;
            float4 v = *(const float4*)(Ab + (size_t)r * K + k0 + acol);
            As[acol + 0][r] = v.x; As[acol + 1][r] = v.y;
            As[acol + 2][r] = v.z; As[acol + 3][r] = v.w;
        }
#pragma unroll
        for (int h = 0; h < 2; ++h) {
            int r = brow + h * 8;
            float4 v = *(const float4*)(Bb + (size_t)(k0 + r) * N + bcol);
            *(float4*)&Bs[r][bcol] = v;
        }
        __syncthreads();
#pragma unroll
        for (int kk = 0; kk < BK; ++kk) {
            float a[TM], b[8];
#pragma unroll
            for (int i = 0; i < TM; i += 4) *(float4*)&a[i] = *(const float4*)&As[kk][ty * TM + i];
            *(float4*)&b[0] = *(const float4*)&Bs[kk][tx * 4];
            *(float4*)&b[4] = *(const float4*)&Bs[kk][64 + tx * 4];
#pragma unroll
            for (int i = 0; i < TM; ++i)
#pragma unroll
                for (int j = 0; j < 8; ++j)
                    acc[i][j] = fmaf(a[i], b[j], acc[i][j]);
        }
        __syncthreads();
    }
#pragma unroll
    for (int r = 0; r < RANK; ++r) {
        float bv[8];
#pragma unroll
        for (int j = 0; j < 4; ++j) {
            bv[j]     = Bl[(size_t)r * N + n0 + tx * 4 + j];
            bv[4 + j] = Bl[(size_t)r * N + n0 + 64 + tx * 4 + j];
        }
#pragma unroll
        for (int i = 0; i < TM; ++i) {
            float tv = Tl[(size_t)(m0 + ty * TM + i) * RANK + r];
#pragma unroll
            for (int j = 0; j < 8; ++j) acc[i][j] = fmaf(tv, bv[j], acc[i][j]);
        }
    }
#pragma unroll
    for (int i = 0; i < TM; ++i) {
        int m = m0 + ty * TM + i;
        float v[8];
#pragma unroll
        for (int j = 0; j < 8; ++j) { float x = acc[i][j]; v[j] = x > 0.f ? x : 0.f; }
        uint2 p0, p1;
        p0.x = (unsigned)f32_to_bf16(v[0]) | ((unsigned)f32_to_bf16(v[1]) << 16);
        p0.y = (unsigned)f32_to_bf16(v[2]) | ((unsigned)f32_to_bf16(v[3]) << 16);
        p1.x = (unsigned)f32_to_bf16(v[4]) | ((unsigned)f32_to_bf16(v[5]) << 16);
        p1.y = (unsigned)f32_to_bf16(v[6]) | ((unsigned)f32_to_bf16(v[7]) << 16);
        *(uint2*)(C + (size_t)m * N + n0 + tx * 4) = p0;
        *(uint2*)(C + (size_t)m * N + n0 + 64 + tx * 4) = p1;
    }
}

__global__ __launch_bounds__(256) void gemm_down_f32(
    const u16* __restrict__ A, const float* __restrict__ B,
    const float* __restrict__ Tl, const float* __restrict__ Bl,
    float* __restrict__ C, int M, int N, int K)
{
    __shared__ float As[BK][BM + 4];
    __shared__ float Bs[BK][BN];
    int tid = threadIdx.x;
    int tx = tid % 16, ty = tid / 16;
    int m0 = blockIdx.y * BM, n0 = blockIdx.x * BN;
    const u16* Ab = A + (size_t)m0 * K;
    const float* Bb = B + n0;
    float acc[TM][8];
#pragma unroll
    for (int i = 0; i < TM; ++i)
#pragma unroll
        for (int j = 0; j < 8; ++j) acc[i][j] = 0.f;

    int arow = tid >> 1, ahalf = (tid & 1) * 8;
    int brow = tid >> 5, bcol = (tid & 31) * 4;

    for (int k0 = 0; k0 < K; k0 += BK) {
        {
            uint4 v = *(const uint4*)(Ab + (size_t)arow * K + k0 + ahalf);
            unsigned int w_[4] = {v.x, v.y, v.z, v.w};
#pragma unroll
            for (int qq = 0; qq < 4; ++qq) {
                As[ahalf + 2 * qq + 0][arow] = bf16_to_f32((u16)(w_[qq] & 0xffffu));
                As[ahalf + 2 * qq + 1][arow] = bf16_to_f32((u16)(w_[qq] >> 16));
            }
        }
#pragma unroll
        for (int h = 0; h < 2; ++h) {
            int r = brow + h * 8;
            float4 v = *(const float4*)(Bb + (size_t)(k0 + r) * N + bcol);
            *(float4*)&Bs[r][bcol] = v;
        }
        __syncthreads();
#pragma unroll
        for (int kk = 0; kk < BK; ++kk) {
            float a[TM], b[8];
#pragma unroll
            for (int i = 0; i < TM; i += 4) *(float4*)&a[i] = *(const float4*)&As[kk][ty * TM + i];
            *(float4*)&b[0] = *(const float4*)&Bs[kk][tx * 4];
            *(float4*)&b[4] = *(const float4*)&Bs[kk][64 + tx * 4];
#pragma unroll
            for (int i = 0; i < TM; ++i)
#pragma unroll
                for (int j = 0; j < 8; ++j)
                    acc[i][j] = fmaf(a[i], b[j], acc[i][j]);
        }
        __syncthreads();
    }
#pragma unroll
    for (int r = 0; r < RANK; ++r) {
        float bv[8];
#pragma unroll
        for (int j = 0; j < 4; ++j) {
            bv[j]     = Bl[(size_t)r * N + n0 + tx * 4 + j];
            bv[4 + j] = Bl[(size_t)r * N + n0 + 64 + tx * 4 + j];
        }
#pragma unroll
        for (int i = 0; i < TM; ++i) {
            float tv = Tl[(size_t)(m0 + ty * TM + i) * RANK + r];
#pragma unroll
            for (int j = 0; j < 8; ++j) acc[i][j] = fmaf(tv, bv[j], acc[i][j]);
        }
    }
#pragma unroll
    for (int i = 0; i < TM; ++i) {
        int m = m0 + ty * TM + i;
        *(float4*)(C + (size_t)m * N + n0 + tx * 4)      = *(float4*)&acc[i][0];
        *(float4*)(C + (size_t)m * N + n0 + 64 + tx * 4) = *(float4*)&acc[i][4];
    }
}

// old 256-thread down MFMA (mid tier, verified r2/r3)
__global__ __launch_bounds__(256) void gemm_down_mfma(
    const u16* __restrict__ x2, const u16* __restrict__ wdt,
    const float* __restrict__ t2, const float* __restrict__ dnB,
    float* __restrict__ out)
{
    __shared__ u16 As[TILE_SH], Bs[TILE_SH];
    int tid = threadIdx.x, lane = tid & 63, wid = tid >> 6;
    int wr = wid >> 1, wc = wid & 1;
    int col = lane & 15, q = lane >> 4;
    int m0 = blockIdx.y * 128, n0 = blockIdx.x * 128;

    f32x4 acc[4][4];
#pragma unroll
    for (int i = 0; i < 4; ++i)
#pragma unroll
        for (int j = 0; j < 4; ++j) acc[i][j] = (f32x4){0.f, 0.f, 0.f, 0.f};

    const u16* ga = x2 + (size_t)m0 * INTER;
    const u16* gb = wdt + (size_t)n0 * INTER;

    for (int k0 = 0; k0 < INTER; k0 += 32) {
        // 256-thread staging: 512 chunks over 2 passes
        {
            int wid4 = tid >> 6, lane4 = tid & 63;
#pragma unroll
            for (int h = 0; h < 2; ++h) {
                int ch = h * 256 + wid4 * 64 + lane4;
                int r = ch >> 2;
                int c = (ch & 3) ^ ((r >> 1) & 3);
                const u16* srcA = ga + k0 + (size_t)r * INTER + c * 8;
                u16* dstA = As + (size_t)(h * 256 + wid4 * 64) * 8;
                __builtin_amdgcn_global_load_lds(
                    (const __attribute__((address_space(1))) void*)srcA,
                    (__attribute__((address_space(3))) void*)dstA, 16, 0, 0);
                const u16* srcB = gb + k0 + (size_t)r * INTER + c * 8;
                u16* dstB = Bs + (size_t)(h * 256 + wid4 * 64) * 8;
                __builtin_amdgcn_global_load_lds(
                    (const __attribute__((address_space(1))) void*)srcB,
                    (__attribute__((address_space(3))) void*)dstB, 16, 0, 0);
            }
        }
        __syncthreads();
        bf16x8 af[4];
#pragma unroll
        for (int i = 0; i < 4; ++i) af[i] = read_frag(As, wr * 64 + i * 16 + col, q);
#pragma unroll
        for (int j = 0; j < 4; ++j) {
            bf16x8 bf = read_frag(Bs, wc * 64 + j * 16 + col, q);
#pragma unroll
            for (int i = 0; i < 4; ++i)
                acc[i][j] = __builtin_amdgcn_mfma_f32_16x16x32_bf16(af[i], bf, acc[i][j], 0, 0, 0);
        }
        __syncthreads();
    }
    for (int idx = tid; idx < 128 * 32; idx += 256) {
        int r = idx >> 5, c16 = idx & 31;
        float tv = (c16 < RANK) ? t2[(size_t)(m0 + r) * RANK + c16] : 0.f;
        float uv = (c16 < RANK) ? dnB[(size_t)c16 * HIDDEN + n0 + r] : 0.f;
        int pos = swz_chunk(r, c16 >> 3) * 8 + (c16 & 7);
        As[pos] = f32_to_bf16(tv);
        Bs[pos] = f32_to_bf16(uv);
    }
    __syncthreads();
    {
        bf16x8 af[4];
#pragma unroll
        for (int i = 0; i < 4; ++i) af[i] = read_frag(As, wr * 64 + i * 16 + col, q);
#pragma unroll
        for (int j = 0; j < 4; ++j) {
            bf16x8 bf = read_frag(Bs, wc * 64 + j * 16 + col, q);
#pragma unroll
            for (int i = 0; i < 4; ++i)
                acc[i][j] = __builtin_amdgcn_mfma_f32_16x16x32_bf16(af[i], bf, acc[i][j], 0, 0, 0);
        }
    }
#pragma unroll
    for (int i = 0; i < 4; ++i)
#pragma unroll
        for (int j = 0; j < 4; ++j) {
            int n = n0 + wc * 64 + j * 16 + col;
#pragma unroll
            for (int reg = 0; reg < 4; ++reg) {
                int m = m0 + wr * 64 + i * 16 + q * 4 + reg;
                out[(size_t)m * HIDDEN + n] = acc[i][j][reg];
            }
        }
}

// ============================================================================
// zero-count / top-k / gather
// ============================================================================
__global__ __launch_bounds__(256) void count_zeros(
    const u16* __restrict__ X2, int* __restrict__ counts)
{
    int i = blockIdx.x * 256 + threadIdx.x;
    int b = blockIdx.y;
    int s0 = blockIdx.z * 256;
    const u16* p = X2 + ((size_t)(b * SEQ + s0)) * INTER + i;
    int c = 0;
    for (int s = 0; s < 256; ++s) c += (p[(size_t)s * INTER] == 0) ? 1 : 0;
    atomicAdd(&counts[b * INTER + i], c);
}

__global__ __launch_bounds__(256) void topk10(
    const int* __restrict__ counts, int* __restrict__ topidx)
{
    __shared__ int keys[INTER];
    __shared__ int red[256];
    int b = blockIdx.x;
    for (int i = threadIdx.x; i < INTER; i += 256)
        keys[i] = (counts[b * INTER + i] << 13) | i;
    __syncthreads();
    for (int sel = 0; sel < KSAVE; ++sel) {
        int best = 0x7fffffff;
        for (int i = threadIdx.x; i < INTER; i += 256)
            best = min(best, keys[i]);
        red[threadIdx.x] = best;
        __syncthreads();
        for (int off = 128; off > 0; off >>= 1) {
            if (threadIdx.x < off) red[threadIdx.x] = min(red[threadIdx.x], red[threadIdx.x + off]);
            __syncthreads();
        }
        int bestkey = red[0];
        if (threadIdx.x == 0) {
            topidx[b * KSAVE + sel] = bestkey & 0x1fff;
            keys[bestkey & 0x1fff] = 0x7fffffff;
        }
        __syncthreads();
    }
}

__global__ __launch_bounds__(256) void gather_save(
    const u16* __restrict__ X2, const int* __restrict__ topidx,
    float* __restrict__ out2)
{
    int t = blockIdx.x * 256 + threadIdx.x;
    if (t >= BATCH * SEQ * KSAVE) return;
    int j = t % KSAVE;
    int s = (t / KSAVE) % SEQ;
    int b = t / (KSAVE * SEQ);
    int idx = topidx[b * KSAVE + j];
    out2[t] = bf16_to_f32(X2[((size_t)(b * SEQ + s)) * INTER + idx]);
}

// ============================================================================
extern "C" void kernel_launch(void* const* d_in, const int* in_sizes, int n_in,
                              void* d_out, int out_size, void* d_ws, size_t ws_size,
                              hipStream_t stream)
{
    const float* x1   = (const float*)d_in[0];
    const float* w_up = (const float*)d_in[1];
    const float* upA  = (const float*)d_in[2];
    const float* upB  = (const float*)d_in[3];
    const float* w_dn = (const float*)d_in[4];
    const float* dnA  = (const float*)d_in[5];
    const float* dnB  = (const float*)d_in[6];
    float* out = (float*)d_out;
    char* ws = (char*)d_ws;

    const size_t X2B   = (size_t)MROWS * INTER * 2;          // 134217728
    const size_t WHALF = (size_t)NHALF * HIDDEN * 2;         // 16777216
    const size_t WSPL  = (size_t)HIDDEN * INTER * 2;         // 33554432
    const size_t TB    = (size_t)MROWS * RANK * 4;           // 524288
    const size_t CNTB  = (size_t)BATCH * INTER * 4;          // 131072

    size_t fast_need = X2B + 2 * WHALF + 2 * TB + CNTB + 512 + 4 * (size_t)FIXCAP;
    size_t mid_need  = X2B + WSPL + 2 * TB + CNTB + 512;

    u16* x2 = (u16*)ws;
    size_t off = X2B;

    if (ws_size >= fast_need) {
        // ---- FAST: 128x256 MFMA both GEMMs; fused count; fixup adjusts ----
        u16* wth = (u16*)(ws + off);            off += WHALF;
        u16* wtl = (u16*)(ws + off);            off += WHALF;
        float* t1 = (float*)(ws + off);         off += TB;
        float* t2 = (float*)(ws + off);         off += TB;
        int* counts = (int*)(ws + off);         off += CNTB;
        int* topidx = (int*)(ws + off);         off += 256;
        unsigned* fixctr = (unsigned*)(ws + off); off += 256;
        unsigned* fixlist = (unsigned*)(ws + off);
        u16* wdt = wth;   // w_dn^T (WSPL bytes) aliases wth+wtl (dead after up)

        hipMemsetAsync(counts, 0, CNTB, stream);
        hipMemsetAsync(fixctr, 0, 4, stream);

        rowdot16_f32<<<MROWS, 256, 0, stream>>>(x1, upA, t1, HIDDEN);

        for (int half = 0; half < 2; ++half) {
            int noff = half * NHALF;
            transpose_cvt<true><<<dim3(NHALF / 32, HIDDEN / 32), 256, 0, stream>>>(
                w_up + noff, wth, wtl, HIDDEN, INTER);
            gemm_up_mfma3<<<dim3(NHALF / 256, MROWS / 128), 512, 0, stream>>>(
                x1, wth, wtl, t1, upB, x2, counts, fixctr, fixlist, noff);
        }
        fixup_kernel<<<256, 256, 0, stream>>>(x1, w_up, t1, upB, fixctr, fixlist, x2, counts);

        topk10<<<BATCH, 256, 0, stream>>>(counts, topidx);
        gather_save<<<(BATCH * SEQ * KSAVE + 255) / 256, 256, 0, stream>>>(
            x2, topidx, out + (size_t)MROWS * HIDDEN);

        transpose_cvt<false><<<dim3(HIDDEN / 32, INTER / 32), 256, 0, stream>>>(
            w_dn, wdt, nullptr, INTER, HIDDEN);
        rowdot16_bf16<<<MROWS, 256, 0, stream>>>(x2, dnA, t2, INTER);
        gemm_down_mfma2<<<dim3(HIDDEN / 256, MROWS / 128), 512, 0, stream>>>(
            x2, wdt, t2, dnB, out);
    } else if (ws_size >= mid_need) {
        // ---- MID: fp32 up + 256-thr MFMA down (verified r2) ----
        u16* wdt = (u16*)(ws + off);            off += WSPL;
        float* t1 = (float*)(ws + off);         off += TB;
        float* t2 = (float*)(ws + off);         off += TB;
        int* counts = (int*)(ws + off);         off += CNTB;
        int* topidx = (int*)(ws + off);

        hipMemsetAsync(counts, 0, CNTB, stream);
        rowdot16_f32<<<MROWS, 256, 0, stream>>>(x1, upA, t1, HIDDEN);
        gemm_up_f32<<<dim3(INTER / BN, MROWS / BM), 256, 0, stream>>>(
            x1, w_up, t1, upB, x2, MROWS, INTER, HIDDEN);
        count_zeros<<<dim3(INTER / 256, BATCH, SEQ / 256), 256, 0, stream>>>(x2, counts);
        topk10<<<BATCH, 256, 0, stream>>>(counts, topidx);
        gather_save<<<(BATCH * SEQ * KSAVE + 255) / 256, 256, 0, stream>>>(
            x2, topidx, out + (size_t)MROWS * HIDDEN);
        transpose_cvt<false><<<dim3(HIDDEN / 32, INTER / 32), 256, 0, stream>>>(
            w_dn, wdt, nullptr, INTER, HIDDEN);
        rowdot16_bf16<<<MROWS, 256, 0, stream>>>(x2, dnA, t2, INTER);
        gemm_down_mfma<<<dim3(HIDDEN / 128, MROWS / 128), 256, 0, stream>>>(
            x2, wdt, t2, dnB, out);
    } else {
        // ---- LOW: fp32 both ----
        float* t1 = (float*)(ws + off);         off += TB;
        float* t2 = (float*)(ws + off);         off += TB;
        int* counts = (int*)(ws + off);         off += CNTB;
        int* topidx = (int*)(ws + off);

        hipMemsetAsync(counts, 0, CNTB, stream);
        rowdot16_f32<<<MROWS, 256, 0, stream>>>(x1, upA, t1, HIDDEN);
        gemm_up_f32<<<dim3(INTER / BN, MROWS / BM), 256, 0, stream>>>(
            x1, w_up, t1, upB, x2, MROWS, INTER, HIDDEN);
        count_zeros<<<dim3(INTER / 256, BATCH, SEQ / 256), 256, 0, stream>>>(x2, counts);
        topk10<<<BATCH, 256, 0, stream>>>(counts, topidx);
        gather_save<<<(BATCH * SEQ * KSAVE + 255) / 256, 256, 0, stream>>>(
            x2, topidx, out + (size_t)MROWS * HIDDEN);
        rowdot16_bf16<<<MROWS, 256, 0, stream>>>(x2, dnA, t2, INTER);
        gemm_down_f32<<<dim3(HIDDEN / BN, MROWS / BM), 256, 0, stream>>>(
            x2, w_dn, t2, dnB, out, MROWS, HIDDEN, INTER);
    }
}

// Round 5
// 1825.929 us; speedup vs baseline: 1.2365x; 1.2365x over previous
//
#include <hip/hip_runtime.h>
#include <stdint.h>

#define HIDDEN 2048
#define INTER 8192
#define RANK 16
#define BATCH 4
#define SEQ 2048
#define MROWS (BATCH * SEQ)   // 8192
#define KSAVE 10
#define FIXCAP (1u << 16)
#define FIX_TAU 1.2e-4f
#define NHALF 4096

typedef unsigned short u16;
typedef __attribute__((ext_vector_type(8))) __bf16 bf16x8;
typedef __attribute__((ext_vector_type(4))) float f32x4;

__device__ __forceinline__ float bf16_to_f32(u16 h) {
    return __uint_as_float(((unsigned int)h) << 16);
}
__device__ __forceinline__ u16 f32_to_bf16(float f) {
    unsigned int u = __float_as_uint(f);
    u += 0x7fffu + ((u >> 16) & 1u);   // RNE; finite inputs
    return (u16)(u >> 16);
}
__device__ __forceinline__ void split_bf16(float v, u16& h, u16& l) {
    h = f32_to_bf16(v);
    l = f32_to_bf16(v - bf16_to_f32(h));
}

// ============================================================================
// MFMA machinery (16x16x32 bf16). LDS tiles: rows of 32 k as 4 chunks of 16B,
// chunk index = r*4 + (c ^ ((r>>1)&3))  (verified conflict-free r3/r4).
// ============================================================================
#define TILE_SH (128 * 32)   // u16 elements per 128-row tile (8 KB)

__device__ __forceinline__ int swz_chunk(int r, int c) {
    return r * 4 + (c ^ ((r >> 1) & 3));
}

// 256-thread staging of a 128x32 tile (512 chunks, 2 passes)
__device__ __forceinline__ void stage_tile256(const u16* g, int ldk, u16* lds, int wid, int lane) {
#pragma unroll
    for (int h = 0; h < 2; ++h) {
        int ch = h * 256 + wid * 64 + lane;
        int r = ch >> 2;
        int c = (ch & 3) ^ ((r >> 1) & 3);
        const u16* src = g + (size_t)r * ldk + c * 8;
        u16* dst = lds + (size_t)(h * 256 + wid * 64) * 8;   // wave-uniform base
        __builtin_amdgcn_global_load_lds(
            (const __attribute__((address_space(1))) void*)src,
            (__attribute__((address_space(3))) void*)dst, 16, 0, 0);
    }
}

// 512-thread staging of NCH chunks
template <int NCH>
__device__ __forceinline__ void stage_tileN(const u16* g, int ldk, u16* lds, int tid) {
    int wid = tid >> 6, lane = tid & 63;
#pragma unroll
    for (int c0 = 0; c0 < NCH; c0 += 512) {
        int ch = c0 + wid * 64 + lane;
        int r = ch >> 2;
        int c = (ch & 3) ^ ((r >> 1) & 3);
        const u16* src = g + (size_t)r * ldk + c * 8;
        u16* dst = lds + (size_t)(c0 + wid * 64) * 8;
        __builtin_amdgcn_global_load_lds(
            (const __attribute__((address_space(1))) void*)src,
            (__attribute__((address_space(3))) void*)dst, 16, 0, 0);
    }
}

__device__ __forceinline__ bf16x8 read_frag(const u16* lds, int r, int q) {
    return *(const bf16x8*)(lds + swz_chunk(r, q) * 8);
}

// ---------- up GEMM (r3 structure, measured 511us/half): 128x128 tile,
// 256 thr, in-kernel trunc-split A, 3-term split MFMA, relu+bf16 out,
// fused zero-count + borderline fix list ----------
__global__ __launch_bounds__(256) void gemm_up_mfma2(
    const float* __restrict__ x1,
    const u16* __restrict__ wth, const u16* __restrict__ wtl,
    const float* __restrict__ t1, const float* __restrict__ upB,
    u16* __restrict__ x2, int* __restrict__ counts,
    unsigned* __restrict__ fixctr, unsigned* __restrict__ fixlist,
    int noff)
{
    __shared__ u16 Ah[TILE_SH], Al[TILE_SH], Bh[TILE_SH], Bl[TILE_SH];
    int tid = threadIdx.x, lane = tid & 63, wid = tid >> 6;
    int wr = wid >> 1, wc = wid & 1;
    int col = lane & 15, q = lane >> 4;

    // swizzle: groups of 8 N-cols x 64 M-rows for L2 reuse
    int bid = blockIdx.y * gridDim.x + blockIdx.x;   // grid (32, 64) -> 2048
    int g = bid >> 9, within = bid & 511;
    int nb = g * 8 + (within & 7);
    int mb = within >> 3;
    int m0 = mb * 128, n0l = nb * 128, n0g = noff + n0l;

    f32x4 acc[4][4];
#pragma unroll
    for (int i = 0; i < 4; ++i)
#pragma unroll
        for (int j = 0; j < 4; ++j) acc[i][j] = (f32x4){0.f, 0.f, 0.f, 0.f};

    const float* ga = x1 + (size_t)m0 * HIDDEN;
    const u16* gb_h = wth + (size_t)n0l * HIDDEN;
    const u16* gb_l = wtl + (size_t)n0l * HIDDEN;
    int f4 = tid & 7;        // float4 col within 32-k tile
    int rA = tid >> 3;       // base row 0..31

    for (int k0 = 0; k0 < HIDDEN; k0 += 32) {
        stage_tile256(gb_h + k0, HIDDEN, Bh, wid, lane);
        stage_tile256(gb_l + k0, HIDDEN, Bl, wid, lane);
        // A: load fp32, truncation-split hi/lo bf16, store LDS
        float4 v[4];
#pragma unroll
        for (int h = 0; h < 4; ++h)
            v[h] = *(const float4*)(ga + (size_t)(rA + h * 32) * HIDDEN + k0 + f4 * 4);
#pragma unroll
        for (int h = 0; h < 4; ++h) {
            int row = rA + h * 32;
            unsigned hx0 = __float_as_uint(v[h].x) & 0xffff0000u;
            unsigned hx1 = __float_as_uint(v[h].y) & 0xffff0000u;
            unsigned hx2 = __float_as_uint(v[h].z) & 0xffff0000u;
            unsigned hx3 = __float_as_uint(v[h].w) & 0xffff0000u;
            float l0 = v[h].x - __uint_as_float(hx0);
            float l1 = v[h].y - __uint_as_float(hx1);
            float l2 = v[h].z - __uint_as_float(hx2);
            float l3 = v[h].w - __uint_as_float(hx3);
            unsigned lo0 = __float_as_uint(l0) & 0xffff0000u;
            unsigned lo1 = __float_as_uint(l1) & 0xffff0000u;
            unsigned lo2 = __float_as_uint(l2) & 0xffff0000u;
            unsigned lo3 = __float_as_uint(l3) & 0xffff0000u;
            uint2 hp = {(hx0 >> 16) | hx1, (hx2 >> 16) | hx3};
            uint2 lp = {(lo0 >> 16) | lo1, (lo2 >> 16) | lo3};
            int pos = swz_chunk(row, f4 >> 1) * 8 + (f4 & 1) * 4;
            *(uint2*)(Ah + pos) = hp;
            *(uint2*)(Al + pos) = lp;
        }
        __syncthreads();
        bf16x8 ah[4], al[4];
#pragma unroll
        for (int i = 0; i < 4; ++i) {
            int r = wr * 64 + i * 16 + col;
            ah[i] = read_frag(Ah, r, q);
            al[i] = read_frag(Al, r, q);
        }
#pragma unroll
        for (int j = 0; j < 4; ++j) {
            int rr = wc * 64 + j * 16 + col;
            bf16x8 bh = read_frag(Bh, rr, q);
            bf16x8 bl = read_frag(Bl, rr, q);
#pragma unroll
            for (int i = 0; i < 4; ++i) {
                acc[i][j] = __builtin_amdgcn_mfma_f32_16x16x32_bf16(ah[i], bh, acc[i][j], 0, 0, 0);
                acc[i][j] = __builtin_amdgcn_mfma_f32_16x16x32_bf16(al[i], bh, acc[i][j], 0, 0, 0);
                acc[i][j] = __builtin_amdgcn_mfma_f32_16x16x32_bf16(ah[i], bl, acc[i][j], 0, 0, 0);
            }
        }
        __syncthreads();
    }

    // LoRA as one extra split-MFMA K-step (K=16 real + 16 zero pad)
    for (int idx = tid; idx < 4096; idx += 256) {
        int r = idx >> 5, c16 = idx & 31;
        float tv = (c16 < RANK) ? t1[(size_t)(m0 + r) * RANK + c16] : 0.f;
        float uv = (c16 < RANK) ? upB[(size_t)c16 * INTER + n0g + r] : 0.f;
        u16 th, tl2, uh, ul;
        split_bf16(tv, th, tl2);
        split_bf16(uv, uh, ul);
        int pos = swz_chunk(r, c16 >> 3) * 8 + (c16 & 7);
        Ah[pos] = th; Al[pos] = tl2; Bh[pos] = uh; Bl[pos] = ul;
    }
    __syncthreads();
    {
        bf16x8 ah[4], al[4];
#pragma unroll
        for (int i = 0; i < 4; ++i) {
            int r = wr * 64 + i * 16 + col;
            ah[i] = read_frag(Ah, r, q);
            al[i] = read_frag(Al, r, q);
        }
#pragma unroll
        for (int j = 0; j < 4; ++j) {
            int rr = wc * 64 + j * 16 + col;
            bf16x8 bh = read_frag(Bh, rr, q);
            bf16x8 bl = read_frag(Bl, rr, q);
#pragma unroll
            for (int i = 0; i < 4; ++i) {
                acc[i][j] = __builtin_amdgcn_mfma_f32_16x16x32_bf16(ah[i], bh, acc[i][j], 0, 0, 0);
                acc[i][j] = __builtin_amdgcn_mfma_f32_16x16x32_bf16(al[i], bh, acc[i][j], 0, 0, 0);
                acc[i][j] = __builtin_amdgcn_mfma_f32_16x16x32_bf16(ah[i], bl, acc[i][j], 0, 0, 0);
            }
        }
    }

    // epilogue: relu + bf16 store + fix list + fused zero-count
    int b = m0 >> 11;   // batch index (SEQ=2048)
#pragma unroll
    for (int j = 0; j < 4; ++j) {
        int n = n0g + wc * 64 + j * 16 + col;
        int zc = 0;
#pragma unroll
        for (int i = 0; i < 4; ++i) {
#pragma unroll
            for (int reg = 0; reg < 4; ++reg) {
                int m = m0 + wr * 64 + i * 16 + q * 4 + reg;
                float v = acc[i][j][reg];
                if (fabsf(v) < FIX_TAU) {
                    unsigned slot = atomicAdd(fixctr, 1u);
                    if (slot < FIXCAP) fixlist[slot] = ((unsigned)m << 13) | (unsigned)n;
                }
                zc += (v <= 0.f) ? 1 : 0;
                float rv = v > 0.f ? v : 0.f;
                x2[(size_t)m * INTER + n] = f32_to_bf16(rv);
            }
        }
        zc += __shfl_down(zc, 32);
        zc += __shfl_down(zc, 16);
        if (lane < 16) atomicAdd(&counts[b * INTER + n], zc);
    }
}

// ---------- down GEMM: 128x256 tile, 512 thr, bf16 MFMA, fp32 out ----------
__global__ __launch_bounds__(512) void gemm_down_mfma2(
    const u16* __restrict__ x2, const u16* __restrict__ wdt,
    const float* __restrict__ t2, const float* __restrict__ dnB,
    float* __restrict__ out)
{
    __shared__ u16 As[TILE_SH];
    __shared__ u16 Bs[2 * TILE_SH];
    int tid = threadIdx.x, lane = tid & 63, wid = tid >> 6;
    int wr = wid >> 2, wc = wid & 3;
    int col = lane & 15, q = lane >> 4;
    int m0 = blockIdx.y * 128, n0 = blockIdx.x * 256;

    f32x4 acc[4][4];
#pragma unroll
    for (int i = 0; i < 4; ++i)
#pragma unroll
        for (int j = 0; j < 4; ++j) acc[i][j] = (f32x4){0.f, 0.f, 0.f, 0.f};

    const u16* ga = x2 + (size_t)m0 * INTER;
    const u16* gb = wdt + (size_t)n0 * INTER;

    for (int k0 = 0; k0 < INTER; k0 += 32) {
        stage_tileN<512>(ga + k0, INTER, As, tid);
        stage_tileN<1024>(gb + k0, INTER, Bs, tid);
        __syncthreads();
        bf16x8 af[4];
#pragma unroll
        for (int i = 0; i < 4; ++i) af[i] = read_frag(As, wr * 64 + i * 16 + col, q);
#pragma unroll
        for (int j = 0; j < 4; ++j) {
            bf16x8 bf = read_frag(Bs, wc * 64 + j * 16 + col, q);
#pragma unroll
            for (int i = 0; i < 4; ++i)
                acc[i][j] = __builtin_amdgcn_mfma_f32_16x16x32_bf16(af[i], bf, acc[i][j], 0, 0, 0);
        }
        __syncthreads();
    }

    // LoRA extra K-step
    for (int idx = tid; idx < 4096; idx += 512) {
        int r = idx >> 5, c16 = idx & 31;
        float tv = (c16 < RANK) ? t2[(size_t)(m0 + r) * RANK + c16] : 0.f;
        int pos = swz_chunk(r, c16 >> 3) * 8 + (c16 & 7);
        As[pos] = f32_to_bf16(tv);
    }
    for (int idx = tid; idx < 8192; idx += 512) {
        int r = idx >> 5, c16 = idx & 31;
        float uv = (c16 < RANK) ? dnB[(size_t)c16 * HIDDEN + n0 + r] : 0.f;
        int pos = swz_chunk(r, c16 >> 3) * 8 + (c16 & 7);
        Bs[pos] = f32_to_bf16(uv);
    }
    __syncthreads();
    {
        bf16x8 af[4];
#pragma unroll
        for (int i = 0; i < 4; ++i) af[i] = read_frag(As, wr * 64 + i * 16 + col, q);
#pragma unroll
        for (int j = 0; j < 4; ++j) {
            bf16x8 bf = read_frag(Bs, wc * 64 + j * 16 + col, q);
#pragma unroll
            for (int i = 0; i < 4; ++i)
                acc[i][j] = __builtin_amdgcn_mfma_f32_16x16x32_bf16(af[i], bf, acc[i][j], 0, 0, 0);
        }
    }
#pragma unroll
    for (int i = 0; i < 4; ++i)
#pragma unroll
        for (int j = 0; j < 4; ++j) {
            int n = n0 + wc * 64 + j * 16 + col;
#pragma unroll
            for (int reg = 0; reg < 4; ++reg) {
                int m = m0 + wr * 64 + i * 16 + q * 4 + reg;
                out[(size_t)m * HIDDEN + n] = acc[i][j][reg];
            }
        }
}

// ---------- exact fp32 recompute of borderline y1 elements (+count adjust) ----
__global__ __launch_bounds__(256) void fixup_kernel(
    const float* __restrict__ x1, const float* __restrict__ w_up,
    const float* __restrict__ t1, const float* __restrict__ upB,
    const unsigned* __restrict__ fixctr, const unsigned* __restrict__ fixlist,
    u16* __restrict__ x2, int* __restrict__ counts)
{
    unsigned n_items = *fixctr;
    if (n_items > FIXCAP) n_items = FIXCAP;
    int lane = threadIdx.x & 63;
    int gwave = blockIdx.x * 4 + (threadIdx.x >> 6);
    int nwaves = gridDim.x * 4;
    for (unsigned it = gwave; it < n_items; it += nwaves) {
        unsigned code = fixlist[it];
        int m = code >> 13, n = code & 8191;
        float s = 0.f;
        const float* xr = x1 + (size_t)m * HIDDEN;
        for (int k = lane; k < HIDDEN; k += 64)
            s = fmaf(xr[k], w_up[(size_t)k * INTER + n], s);
#pragma unroll
        for (int off = 32; off > 0; off >>= 1) s += __shfl_down(s, off);
        if (lane == 0) {
            float lo = 0.f;
#pragma unroll
            for (int r = 0; r < RANK; ++r)
                lo = fmaf(t1[(size_t)m * RANK + r], upB[(size_t)r * INTER + n], lo);
            float y = s + lo;
            int oldz = (x2[(size_t)m * INTER + n] == 0) ? 1 : 0;
            int newz = (y <= 0.f) ? 1 : 0;
            if (newz != oldz) atomicAdd(&counts[(m >> 11) * INTER + n], newz - oldz);
            x2[(size_t)m * INTER + n] = f32_to_bf16(y > 0.f ? y : 0.f);
        }
    }
}

// ============================================================================
// LoRA input projections — one lane per row, k-split, A reads wave-uniform.
// Replaces one-block-per-row rowdots (4.2 TB L3 traffic -> 64 MB).
// ============================================================================
// t1 partials: [2][MROWS][16], deterministic fixed-order combine
__global__ __launch_bounds__(256) void lora_t1_part(
    const float* __restrict__ X, const float* __restrict__ A,
    float* __restrict__ Tpart)
{
    int m = blockIdx.x * 256 + threadIdx.x;
    int k0 = blockIdx.y * (HIDDEN / 2);
    const float* xr = X + (size_t)m * HIDDEN + k0;
    const float* Ab = A + (size_t)k0 * RANK;
    float acc[RANK];
#pragma unroll
    for (int r = 0; r < RANK; ++r) acc[r] = 0.f;
    for (int k = 0; k < HIDDEN / 2; k += 4) {
        float4 xv = *(const float4*)(xr + k);
        const float* ar = Ab + (size_t)k * RANK;
        float xs[4] = {xv.x, xv.y, xv.z, xv.w};
#pragma unroll
        for (int e = 0; e < 4; ++e)
#pragma unroll
            for (int r = 0; r < RANK; ++r)
                acc[r] = fmaf(xs[e], ar[e * RANK + r], acc[r]);
    }
    float* dst = Tpart + ((size_t)blockIdx.y * MROWS + m) * RANK;
#pragma unroll
    for (int r = 0; r < RANK; ++r) dst[r] = acc[r];
}

__global__ __launch_bounds__(256) void lora_t1_combine(
    const float* __restrict__ Tpart, float* __restrict__ T)
{
    int i = blockIdx.x * 256 + threadIdx.x;   // over MROWS*RANK
    T[i] = Tpart[i] + Tpart[(size_t)MROWS * RANK + i];
}

// t2: bf16 X, k-split 8, fp32 atomics into zeroed T
__global__ __launch_bounds__(256) void lora_t2_atomic(
    const u16* __restrict__ X, const float* __restrict__ A,
    float* __restrict__ T)
{
    int m = blockIdx.x * 256 + threadIdx.x;
    const int kn = INTER / 8;
    int k0 = blockIdx.y * kn;
    const u16* xr = X + (size_t)m * INTER + k0;
    const float* Ab = A + (size_t)k0 * RANK;
    float acc[RANK];
#pragma unroll
    for (int r = 0; r < RANK; ++r) acc[r] = 0.f;
    for (int k = 0; k < kn; k += 8) {
        uint4 p = *(const uint4*)(xr + k);
        unsigned w_[4] = {p.x, p.y, p.z, p.w};
        const float* ar = Ab + (size_t)k * RANK;
#pragma unroll
        for (int e = 0; e < 4; ++e) {
            float v0 = bf16_to_f32((u16)(w_[e] & 0xffffu));
            float v1 = bf16_to_f32((u16)(w_[e] >> 16));
#pragma unroll
            for (int r = 0; r < RANK; ++r)
                acc[r] = fmaf(v0, ar[(2 * e) * RANK + r],
                         fmaf(v1, ar[(2 * e + 1) * RANK + r], acc[r]));
        }
    }
#pragma unroll
    for (int r = 0; r < RANK; ++r)
        atomicAdd(&T[(size_t)m * RANK + r], acc[r]);
}

// ============================================================================
// transpose+convert: in [R][C-range] f32 -> out [Crange][R] bf16 (hi / hi+lo)
// ============================================================================
template <bool SPLIT>
__global__ __launch_bounds__(256) void transpose_cvt(
    const float* __restrict__ in, u16* __restrict__ outh, u16* __restrict__ outl,
    int R, int C)
{
    __shared__ float t[32][33];
    int x = threadIdx.x & 31, y = threadIdx.x >> 5;
    int r0 = blockIdx.y * 32, c0 = blockIdx.x * 32;
#pragma unroll
    for (int p = 0; p < 4; ++p)
        t[y + p * 8][x] = in[(size_t)(r0 + y + p * 8) * C + c0 + x];
    __syncthreads();
#pragma unroll
    for (int p = 0; p < 4; ++p) {
        float v = t[x][y + p * 8];
        u16 h = f32_to_bf16(v);
        outh[(size_t)(c0 + y + p * 8) * R + r0 + x] = h;
        if (SPLIT)
            outl[(size_t)(c0 + y + p * 8) * R + r0 + x] = f32_to_bf16(v - bf16_to_f32(h));
    }
}

// ============================================================================
// legacy rowdots (mid/low fallback only)
// ============================================================================
__global__ __launch_bounds__(256) void rowdot16_f32(
    const float* __restrict__ X, const float* __restrict__ A,
    float* __restrict__ T, int K)
{
    __shared__ float red[256][RANK + 1];
    int m = blockIdx.x;
    const float* xr = X + (size_t)m * K;
    float acc[RANK];
#pragma unroll
    for (int r = 0; r < RANK; ++r) acc[r] = 0.f;
    for (int k = threadIdx.x; k < K; k += 256) {
        float xv = xr[k];
        const float* ar = A + (size_t)k * RANK;
#pragma unroll
        for (int r = 0; r < RANK; ++r) acc[r] = fmaf(xv, ar[r], acc[r]);
    }
#pragma unroll
    for (int r = 0; r < RANK; ++r) red[threadIdx.x][r] = acc[r];
    __syncthreads();
    for (int off = 128; off > 0; off >>= 1) {
        if (threadIdx.x < off) {
#pragma unroll
            for (int r = 0; r < RANK; ++r)
                red[threadIdx.x][r] += red[threadIdx.x + off][r];
        }
        __syncthreads();
    }
    if (threadIdx.x < RANK) T[(size_t)m * RANK + threadIdx.x] = red[0][threadIdx.x];
}

__global__ __launch_bounds__(256) void rowdot16_bf16(
    const u16* __restrict__ X, const float* __restrict__ A,
    float* __restrict__ T, int K)
{
    __shared__ float red[256][RANK + 1];
    int m = blockIdx.x;
    const u16* xr = X + (size_t)m * K;
    float acc[RANK];
#pragma unroll
    for (int r = 0; r < RANK; ++r) acc[r] = 0.f;
    for (int k = threadIdx.x; k < K; k += 256) {
        float xv = bf16_to_f32(xr[k]);
        const float* ar = A + (size_t)k * RANK;
#pragma unroll
        for (int r = 0; r < RANK; ++r) acc[r] = fmaf(xv, ar[r], acc[r]);
    }
#pragma unroll
    for (int r = 0; r < RANK; ++r) red[threadIdx.x][r] = acc[r];
    __syncthreads();
    for (int off = 128; off > 0; off >>= 1) {
        if (threadIdx.x < off) {
#pragma unroll
            for (int r = 0; r < RANK; ++r)
                red[threadIdx.x][r] += red[threadIdx.x + off][r];
        }
        __syncthreads();
    }
    if (threadIdx.x < RANK) T[(size_t)m * RANK + threadIdx.x] = red[0][threadIdx.x];
}

// ============================================================================
// fp32 VALU GEMM fallbacks + 256-thr down MFMA (mid tier) — unchanged
// ============================================================================
#define BM 128
#define BN 128
#define BK 16
#define TM 8

__global__ __launch_bounds__(256) void gemm_up_f32(
    const float* __restrict__ A, const float* __restrict__ B,
    const float* __restrict__ Tl, const float* __restrict__ Bl,
    u16* __restrict__ C, int M, int N, int K)
{
    __shared__ float As[BK][BM + 4];
    __shared__ float Bs[BK][BN];
    int tid = threadIdx.x;
    int tx = tid % 16, ty = tid / 16;
    int m0 = blockIdx.y * BM, n0 = blockIdx.x * BN;
    const float* Ab = A + (size_t)m0 * K;
    const float* Bb = B + n0;
    float acc[TM][8];
#pragma unroll
    for (int i = 0; i < TM; ++i)
#pragma unroll
        for (int j = 0; j < 8; ++j) acc[i][j] = 0.f;

    int arow = tid >> 2, acol = (tid & 3) * 4;
    int brow = tid >> 5, bcol = (tid & 31) * 4;

    for (int k0 = 0; k0 < K; k0 += BK) {
#pragma unroll
        for (int h = 0; h < 2; ++h) {
            int r = arow + h * 64;
            float4 v = *(const float4*)(Ab + (size_t)r * K + k0 + acol);
            As[acol + 0][r] = v.x; As[acol + 1][r] = v.y;
            As[acol + 2][r] = v.z; As[acol + 3][r] = v.w;
        }
#pragma unroll
        for (int h = 0; h < 2; ++h) {
            int r = brow + h * 8;
            float4 v = *(const float4*)(Bb + (size_t)(k0 + r) * N + bcol);
            *(float4*)&Bs[r][bcol] = v;
        }
        __syncthreads();
#pragma unroll
        for (int kk = 0; kk < BK; ++kk) {
            float a[TM], b[8];
#pragma unroll
            for (int i = 0; i < TM; i += 4) *(float4*)&a[i] = *(const float4*)&As[kk][ty * TM + i];
            *(float4*)&b[0] = *(const float4*)&Bs[kk][tx * 4];
            *(float4*)&b[4] = *(const float4*)&Bs[kk][64 + tx * 4];
#pragma unroll
            for (int i = 0; i < TM; ++i)
#pragma unroll
                for (int j = 0; j < 8; ++j)
                    acc[i][j] = fmaf(a[i], b[j], acc[i][j]);
        }
        __syncthreads();
    }
#pragma unroll
    for (int r = 0; r < RANK; ++r) {
        float bv[8];
#pragma unroll
        for (int j = 0; j < 4; ++j) {
            bv[j]     = Bl[(size_t)r * N + n0 + tx * 4 + j];
            bv[4 + j] = Bl[(size_t)r * N + n0 + 64 + tx * 4 + j];
        }
#pragma unroll
        for (int i = 0; i < TM; ++i) {
            float tv = Tl[(size_t)(m0 + ty * TM + i) * RANK + r];
#pragma unroll
            for (int j = 0; j < 8; ++j) acc[i][j] = fmaf(tv, bv[j], acc[i][j]);
        }
    }
#pragma unroll
    for (int i = 0; i < TM; ++i) {
        int m = m0 + ty * TM + i;
        float v[8];
#pragma unroll
        for (int j = 0; j < 8; ++j) { float x = acc[i][j]; v[j] = x > 0.f ? x : 0.f; }
        uint2 p0, p1;
        p0.x = (unsigned)f32_to_bf16(v[0]) | ((unsigned)f32_to_bf16(v[1]) << 16);
        p0.y = (unsigned)f32_to_bf16(v[2]) | ((unsigned)f32_to_bf16(v[3]) << 16);
        p1.x = (unsigned)f32_to_bf16(v[4]) | ((unsigned)f32_to_bf16(v[5]) << 16);
        p1.y = (unsigned)f32_to_bf16(v[6]) | ((unsigned)f32_to_bf16(v[7]) << 16);
        *(uint2*)(C + (size_t)m * N + n0 + tx * 4) = p0;
        *(uint2*)(C + (size_t)m * N + n0 + 64 + tx * 4) = p1;
    }
}

__global__ __launch_bounds__(256) void gemm_down_f32(
    const u16* __restrict__ A, const float* __restrict__ B,
    const float* __restrict__ Tl, const float* __restrict__ Bl,
    float* __restrict__ C, int M, int N, int K)
{
    __shared__ float As[BK][BM + 4];
    __shared__ float Bs[BK][BN];
    int tid = threadIdx.x;
    int tx = tid % 16, ty = tid / 16;
    int m0 = blockIdx.y * BM, n0 = blockIdx.x * BN;
    const u16* Ab = A + (size_t)m0 * K;
    const float* Bb = B + n0;
    float acc[TM][8];
#pragma unroll
    for (int i = 0; i < TM; ++i)
#pragma unroll
        for (int j = 0; j < 8; ++j) acc[i][j] = 0.f;

    int arow = tid >> 1, ahalf = (tid & 1) * 8;
    int brow = tid >> 5, bcol = (tid & 31) * 4;

    for (int k0 = 0; k0 < K; k0 += BK) {
        {
            uint4 v = *(const uint4*)(Ab + (size_t)arow * K + k0 + ahalf);
            unsigned int w_[4] = {v.x, v.y, v.z, v.w};
#pragma unroll
            for (int qq = 0; qq < 4; ++qq) {
                As[ahalf + 2 * qq + 0][arow] = bf16_to_f32((u16)(w_[qq] & 0xffffu));
                As[ahalf + 2 * qq + 1][arow] = bf16_to_f32((u16)(w_[qq] >> 16));
            }
        }
#pragma unroll
        for (int h = 0; h < 2; ++h) {
            int r = brow + h * 8;
            float4 v = *(const float4*)(Bb + (size_t)(k0 + r) * N + bcol);
            *(float4*)&Bs[r][bcol] = v;
        }
        __syncthreads();
#pragma unroll
        for (int kk = 0; kk < BK; ++kk) {
            float a[TM], b[8];
#pragma unroll
            for (int i = 0; i < TM; i += 4) *(float4*)&a[i] = *(const float4*)&As[kk][ty * TM + i];
            *(float4*)&b[0] = *(const float4*)&Bs[kk][tx * 4];
            *(float4*)&b[4] = *(const float4*)&Bs[kk][64 + tx * 4];
#pragma unroll
            for (int i = 0; i < TM; ++i)
#pragma unroll
                for (int j = 0; j < 8; ++j)
                    acc[i][j] = fmaf(a[i], b[j], acc[i][j]);
        }
        __syncthreads();
    }
#pragma unroll
    for (int r = 0; r < RANK; ++r) {
        float bv[8];
#pragma unroll
        for (int j = 0; j < 4; ++j) {
            bv[j]     = Bl[(size_t)r * N + n0 + tx * 4 + j];
            bv[4 + j] = Bl[(size_t)r * N + n0 + 64 + tx * 4 + j];
        }
#pragma unroll
        for (int i = 0; i < TM; ++i) {
            float tv = Tl[(size_t)(m0 + ty * TM + i) * RANK + r];
#pragma unroll
            for (int j = 0; j < 8; ++j) acc[i][j] = fmaf(tv, bv[j], acc[i][j]);
        }
    }
#pragma unroll
    for (int i = 0; i < TM; ++i) {
        int m = m0 + ty * TM + i;
        *(float4*)(C + (size_t)m * N + n0 + tx * 4)      = *(float4*)&acc[i][0];
        *(float4*)(C + (size_t)m * N + n0 + 64 + tx * 4) = *(float4*)&acc[i][4];
    }
}

// 256-thread down MFMA (mid tier, verified r2/r3)
__global__ __launch_bounds__(256) void gemm_down_mfma(
    const u16* __restrict__ x2, const u16* __restrict__ wdt,
    const float* __restrict__ t2, const float* __restrict__ dnB,
    float* __restrict__ out)
{
    __shared__ u16 As[TILE_SH], Bs[TILE_SH];
    int tid = threadIdx.x, lane = tid & 63, wid = tid >> 6;
    int wr = wid >> 1, wc = wid & 1;
    int col = lane & 15, q = lane >> 4;
    int m0 = blockIdx.y * 128, n0 = blockIdx.x * 128;

    f32x4 acc[4][4];
#pragma unroll
    for (int i = 0; i < 4; ++i)
#pragma unroll
        for (int j = 0; j < 4; ++j) acc[i][j] = (f32x4){0.f, 0.f, 0.f, 0.f};

    const u16* ga = x2 + (size_t)m0 * INTER;
    const u16* gb = wdt + (size_t)n0 * INTER;

    for (int k0 = 0; k0 < INTER; k0 += 32) {
        stage_tile256(ga + k0, INTER, As, wid, lane);
        stage_tile256(gb + k0, INTER, Bs, wid, lane);
        __syncthreads();
        bf16x8 af[4];
#pragma unroll
        for (int i = 0; i < 4; ++i) af[i] = read_frag(As, wr * 64 + i * 16 + col, q);
#pragma unroll
        for (int j = 0; j < 4; ++j) {
            bf16x8 bf = read_frag(Bs, wc * 64 + j * 16 + col, q);
#pragma unroll
            for (int i = 0; i < 4; ++i)
                acc[i][j] = __builtin_amdgcn_mfma_f32_16x16x32_bf16(af[i], bf, acc[i][j], 0, 0, 0);
        }
        __syncthreads();
    }
    for (int idx = tid; idx < 128 * 32; idx += 256) {
        int r = idx >> 5, c16 = idx & 31;
        float tv = (c16 < RANK) ? t2[(size_t)(m0 + r) * RANK + c16] : 0.f;
        float uv = (c16 < RANK) ? dnB[(size_t)c16 * HIDDEN + n0 + r] : 0.f;
        int pos = swz_chunk(r, c16 >> 3) * 8 + (c16 & 7);
        As[pos] = f32_to_bf16(tv);
        Bs[pos] = f32_to_bf16(uv);
    }
    __syncthreads();
    {
        bf16x8 af[4];
#pragma unroll
        for (int i = 0; i < 4; ++i) af[i] = read_frag(As, wr * 64 + i * 16 + col, q);
#pragma unroll
        for (int j = 0; j < 4; ++j) {
            bf16x8 bf = read_frag(Bs, wc * 64 + j * 16 + col, q);
#pragma unroll
            for (int i = 0; i < 4; ++i)
                acc[i][j] = __builtin_amdgcn_mfma_f32_16x16x32_bf16(af[i], bf, acc[i][j], 0, 0, 0);
        }
    }
#pragma unroll
    for (int i = 0; i < 4; ++i)
#pragma unroll
        for (int j = 0; j < 4; ++j) {
            int n = n0 + wc * 64 + j * 16 + col;
#pragma unroll
            for (int reg = 0; reg < 4; ++reg) {
                int m = m0 + wr * 64 + i * 16 + q * 4 + reg;
                out[(size_t)m * HIDDEN + n] = acc[i][j][reg];
            }
        }
}

// ============================================================================
// zero-count (mid/low) / top-k / gather
// ============================================================================
__global__ __launch_bounds__(256) void count_zeros(
    const u16* __restrict__ X2, int* __restrict__ counts)
{
    int i = blockIdx.x * 256 + threadIdx.x;
    int b = blockIdx.y;
    int s0 = blockIdx.z * 256;
    const u16* p = X2 + ((size_t)(b * SEQ + s0)) * INTER + i;
    int c = 0;
    for (int s = 0; s < 256; ++s) c += (p[(size_t)s * INTER] == 0) ? 1 : 0;
    atomicAdd(&counts[b * INTER + i], c);
}

__global__ __launch_bounds__(256) void topk10(
    const int* __restrict__ counts, int* __restrict__ topidx)
{
    __shared__ int keys[INTER];
    __shared__ int red[256];
    int b = blockIdx.x;
    for (int i = threadIdx.x; i < INTER; i += 256)
        keys[i] = (counts[b * INTER + i] << 13) | i;
    __syncthreads();
    for (int sel = 0; sel < KSAVE; ++sel) {
        int best = 0x7fffffff;
        for (int i = threadIdx.x; i < INTER; i += 256)
            best = min(best, keys[i]);
        red[threadIdx.x] = best;
        __syncthreads();
        for (int off = 128; off > 0; off >>= 1) {
            if (threadIdx.x < off) red[threadIdx.x] = min(red[threadIdx.x], red[threadIdx.x + off]);
            __syncthreads();
        }
        int bestkey = red[0];
        if (threadIdx.x == 0) {
            topidx[b * KSAVE + sel] = bestkey & 0x1fff;
            keys[bestkey & 0x1fff] = 0x7fffffff;
        }
        __syncthreads();
    }
}

__global__ __launch_bounds__(256) void gather_save(
    const u16* __restrict__ X2, const int* __restrict__ topidx,
    float* __restrict__ out2)
{
    int t = blockIdx.x * 256 + threadIdx.x;
    if (t >= BATCH * SEQ * KSAVE) return;
    int j = t % KSAVE;
    int s = (t / KSAVE) % SEQ;
    int b = t / (KSAVE * SEQ);
    int idx = topidx[b * KSAVE + j];
    out2[t] = bf16_to_f32(X2[((size_t)(b * SEQ + s)) * INTER + idx]);
}

// ============================================================================
extern "C" void kernel_launch(void* const* d_in, const int* in_sizes, int n_in,
                              void* d_out, int out_size, void* d_ws, size_t ws_size,
                              hipStream_t stream)
{
    const float* x1   = (const float*)d_in[0];
    const float* w_up = (const float*)d_in[1];
    const float* upA  = (const float*)d_in[2];
    const float* upB  = (const float*)d_in[3];
    const float* w_dn = (const float*)d_in[4];
    const float* dnA  = (const float*)d_in[5];
    const float* dnB  = (const float*)d_in[6];
    float* out = (float*)d_out;
    char* ws = (char*)d_ws;

    const size_t X2B   = (size_t)MROWS * INTER * 2;          // 134217728
    const size_t WHALF = (size_t)NHALF * HIDDEN * 2;         // 16777216
    const size_t WSPL  = (size_t)HIDDEN * INTER * 2;         // 33554432
    const size_t TB    = (size_t)MROWS * RANK * 4;           // 524288
    const size_t CNTB  = (size_t)BATCH * INTER * 4;          // 131072

    size_t fast_need = X2B + 2 * WHALF + 2 * TB + 2 * TB /*t1part*/ + CNTB + 512
                     + 4 * (size_t)FIXCAP;
    size_t mid_need  = X2B + WSPL + 2 * TB + CNTB + 512;

    u16* x2 = (u16*)ws;
    size_t off = X2B;

    if (ws_size >= fast_need) {
        // ---- FAST: MFMA GEMMs (up=r3 128x128, down=128x256), fused count ----
        u16* wth = (u16*)(ws + off);            off += WHALF;
        u16* wtl = (u16*)(ws + off);            off += WHALF;
        float* t1 = (float*)(ws + off);         off += TB;
        float* t2 = (float*)(ws + off);         off += TB;
        float* t1part = (float*)(ws + off);     off += 2 * TB;
        int* counts = (int*)(ws + off);         off += CNTB;
        int* topidx = (int*)(ws + off);         off += 256;
        unsigned* fixctr = (unsigned*)(ws + off); off += 256;
        unsigned* fixlist = (unsigned*)(ws + off);
        u16* wdt = wth;   // w_dn^T (WSPL bytes) aliases wth+wtl (dead after up)

        hipMemsetAsync(counts, 0, CNTB, stream);
        hipMemsetAsync(fixctr, 0, 4, stream);
        hipMemsetAsync(t2, 0, TB, stream);

        // t1 = x1 @ upA (deterministic 2-part)
        lora_t1_part<<<dim3(MROWS / 256, 2), 256, 0, stream>>>(x1, upA, t1part);
        lora_t1_combine<<<MROWS * RANK / 256, 256, 0, stream>>>(t1part, t1);

        for (int half = 0; half < 2; ++half) {
            int noff = half * NHALF;
            transpose_cvt<true><<<dim3(NHALF / 32, HIDDEN / 32), 256, 0, stream>>>(
                w_up + noff, wth, wtl, HIDDEN, INTER);
            gemm_up_mfma2<<<dim3(NHALF / 128, MROWS / 128), 256, 0, stream>>>(
                x1, wth, wtl, t1, upB, x2, counts, fixctr, fixlist, noff);
        }
        fixup_kernel<<<256, 256, 0, stream>>>(x1, w_up, t1, upB, fixctr, fixlist, x2, counts);

        // t2 = x2 @ dnA (post-fixup), k-split 8 + fp32 atomics
        lora_t2_atomic<<<dim3(MROWS / 256, 8), 256, 0, stream>>>(x2, dnA, t2);

        topk10<<<BATCH, 256, 0, stream>>>(counts, topidx);
        gather_save<<<(BATCH * SEQ * KSAVE + 255) / 256, 256, 0, stream>>>(
            x2, topidx, out + (size_t)MROWS * HIDDEN);

        transpose_cvt<false><<<dim3(HIDDEN / 32, INTER / 32), 256, 0, stream>>>(
            w_dn, wdt, nullptr, INTER, HIDDEN);
        gemm_down_mfma2<<<dim3(HIDDEN / 256, MROWS / 128), 512, 0, stream>>>(
            x2, wdt, t2, dnB, out);
    } else if (ws_size >= mid_need) {
        // ---- MID: fp32 up + 256-thr MFMA down ----
        u16* wdt = (u16*)(ws + off);            off += WSPL;
        float* t1 = (float*)(ws + off);         off += TB;
        float* t2 = (float*)(ws + off);         off += TB;
        int* counts = (int*)(ws + off);         off += CNTB;
        int* topidx = (int*)(ws + off);

        hipMemsetAsync(counts, 0, CNTB, stream);
        rowdot16_f32<<<MROWS, 256, 0, stream>>>(x1, upA, t1, HIDDEN);
        gemm_up_f32<<<dim3(INTER / BN, MROWS / BM), 256, 0, stream>>>(
            x1, w_up, t1, upB, x2, MROWS, INTER, HIDDEN);
        count_zeros<<<dim3(INTER / 256, BATCH, SEQ / 256), 256, 0, stream>>>(x2, counts);
        topk10<<<BATCH, 256, 0, stream>>>(counts, topidx);
        gather_save<<<(BATCH * SEQ * KSAVE + 255) / 256, 256, 0, stream>>>(
            x2, topidx, out + (size_t)MROWS * HIDDEN);
        transpose_cvt<false><<<dim3(HIDDEN / 32, INTER / 32), 256, 0, stream>>>(
            w_dn, wdt, nullptr, INTER, HIDDEN);
        rowdot16_bf16<<<MROWS, 256, 0, stream>>>(x2, dnA, t2, INTER);
        gemm_down_mfma<<<dim3(HIDDEN / 128, MROWS / 128), 256, 0, stream>>>(
            x2, wdt, t2, dnB, out);
    } else {
        // ---- LOW: fp32 both ----
        float* t1 = (float*)(ws + off);         off += TB;
        float* t2 = (float*)(ws + off);         off += TB;
        int* counts = (int*)(ws + off);         off += CNTB;
        int* topidx = (int*)(ws + off);

        hipMemsetAsync(counts, 0, CNTB, stream);
        rowdot16_f32<<<MROWS, 256, 0, stream>>>(x1, upA, t1, HIDDEN);
        gemm_up_f32<<<dim3(INTER / BN, MROWS / BM), 256, 0, stream>>>(
            x1, w_up, t1, upB, x2, MROWS, INTER, HIDDEN);
        count_zeros<<<dim3(INTER / 256, BATCH, SEQ / 256), 256, 0, stream>>>(x2, counts);
        topk10<<<BATCH, 256, 0, stream>>>(counts, topidx);
        gather_save<<<(BATCH * SEQ * KSAVE + 255) / 256, 256, 0, stream>>>(
            x2, topidx, out + (size_t)MROWS * HIDDEN);
        rowdot16_bf16<<<MROWS, 256, 0, stream>>>(x2, dnA, t2, INTER);
        gemm_down_f32<<<dim3(HIDDEN / BN, MROWS / BM), 256, 0, stream>>>(
            x2, w_dn, t2, dnB, out, MROWS, HIDDEN, INTER);
    }
}